// Round 6
// baseline (2956.252 us; speedup 1.0000x reference)
//
#include <hip/hip_runtime.h>
#include <hip/hip_bf16.h>
#include <cstdint>
#include <cstddef>

#define BATCH 32
#define CIN   256
#define COUT  256
#define HH    56
#define WW    56
#define HP    60      // padded rows: 0..57 read; 58/59 slack (zeroed)
#define WPAD  64      // padded cols: 0,57 are conv zero-pad; 58..63 slack (zeroed)
#define KTOT  2304    // 9 * 256

typedef __attribute__((ext_vector_type(4)))  float f32x4;
typedef __attribute__((ext_vector_type(16))) float f32x16;
typedef __attribute__((ext_vector_type(8)))  short short8;

// ---------------- zero only the padding cells of xq (12.4 MB, not 63 MB) ----------------
__global__ void zeropad_kernel(unsigned short* __restrict__ xq)
{
    const int b   = blockIdx.y;
    const int idx = blockIdx.x * 256 + threadIdx.x;   // 0..22527
    const int pos = idx >> 5;
    const int ch  = (idx & 31) * 8;
    int hp, wp;
    if (pos < 256) {                     // rows {0,57,58,59} full
        int r = pos >> 6;
        hp = (r == 0) ? 0 : 56 + r;
        wp = pos & 63;
    } else {                             // rows 1..56, cols {0,57..63}
        int i2 = pos - 256;
        int c  = i2 & 7;
        hp = (i2 >> 3) + 1;
        wp = (c == 0) ? 0 : 56 + c;
    }
    short8 z = {0, 0, 0, 0, 0, 0, 0, 0};
    *reinterpret_cast<short8*>(xq + (((size_t)b * HP + hp) * WPAD + wp) * CIN + ch) = z;
}

// ---------------- BFP quantize + NCHW->padded-NHWC bf16 repack ----------------
__global__ void quant_kernel(const float* __restrict__ x, unsigned short* __restrict__ xq)
{
    const int h   = blockIdx.x;       // 0..55
    const int b   = blockIdx.y;       // 0..31
    const int tid = threadIdx.x;
    const int wv  = tid >> 6;
    const int w   = tid & 63;
    if (w >= WW) return;
    for (int cb = wv; cb < 8; cb += 4) {
        float v[32];
        float mx = 0.f;
        const float* xp = x + (((size_t)b * CIN + cb * 32) * HH + h) * WW + w;
#pragma unroll
        for (int c = 0; c < 32; ++c) {
            float t = xp[(size_t)c * HH * WW];
            v[c] = t;
            mx = fmaxf(mx, fabsf(t));
        }
        float m = fmaxf(mx, 1e-12f);
        int e;
        frexpf(m, &e);
        e -= 1;                                  // exact floor(log2(m))
        e = (e < -64) ? -64 : ((e > 63) ? 63 : e);
        float step = exp2f((float)(e - 7));
        float inv  = exp2f((float)(7 - e));
        unsigned short qb[32];
#pragma unroll
        for (int c = 0; c < 32; ++c) {
            float q = rintf(v[c] * inv);          // round-half-even, matches jnp.round
            q = fminf(fmaxf(q, -128.f), 127.f);
            float val = q * step;                 // exactly representable in bf16
            __hip_bfloat16 bv = __float2bfloat16(val);
            qb[c] = *reinterpret_cast<unsigned short*>(&bv);
        }
        unsigned short* dst = xq + (((size_t)b * HP + (h + 1)) * WPAD + (w + 1)) * CIN + cb * 32;
#pragma unroll
        for (int i = 0; i < 4; ++i)
            *reinterpret_cast<short8*>(dst + i * 8) = *reinterpret_cast<const short8*>(qb + i * 8);
    }
}

// ---------------- weight repack: OIHW fp32 -> [n][j=kh*3+kw][c] bf16 ----------------
__global__ void wrepack_kernel(const float* __restrict__ Wsrc, unsigned short* __restrict__ Wr)
{
    int idx = blockIdx.x * 256 + threadIdx.x;
    if (idx >= COUT * KTOT) return;
    int n = idx / KTOT;
    int r = idx % KTOT;
    int j = r >> 8;    // 0..8
    int c = r & 255;
    float val = Wsrc[((size_t)n * CIN + c) * 9 + j];
    __hip_bfloat16 bv = __float2bfloat16(val);
    Wr[idx] = *reinterpret_cast<unsigned short*>(&bv);
}

// ---------------- implicit-GEMM conv: 256x256 tile, 4 waves x (128x128), 32x32x16 MFMA ----
// Round-6 structure: REG-STAGED double-buffer (T14), 64 KB LDS -> 2 blocks/CU.
//   iter t (buf p = t&1):
//     0. ds_write buf p^1 <- regA (tile t+1 A)   [vmcnt counted by compiler, per-reg]
//     1. ds_read fragments of tile t from buf p
//     2. issue global loads regA <- tile t+2 A
//     3. 32x MFMA 32x32x16
//     4. ds_write buf p^1 <- regB (tile t+1 B)
//     5. issue global loads regB <- tile t+2 B
//     6. lgkmcnt(0); s_barrier
//   WAR: buf p^1 was last read in iter t-1 (before its barrier) -> writes safe.
//   RAW: tile t+1 writes drain at step 6 before iter t+1 reads them.
//   Reg flight: loads issued iter t, ds_written iter t+1 (~1.5 iters > HBM latency).
//
// LDS fragment-order layout per 16 KB buffer: elem ((g*2+kk)*64 + l)*8; lane l
// reads its 16B at byte l*16 within each 1 KB fragment -> conflict-free, and
// ds_write (thread tid writes elem (q*256+tid)*8) is lane-linear -> conflict-free.
#define LGKM0() do { asm volatile("s_waitcnt lgkmcnt(0)" ::: "memory"); } while (0)

#define ITER(T, P) do {                                                                   \
    const int t_ = (T);                                                                   \
    const unsigned short* Ac = As + (P) * 8192;                                           \
    const unsigned short* Bc = Bs + (P) * 8192;                                           \
    unsigned short* Ax = As + ((P) ^ 1) * 8192;                                           \
    unsigned short* Bx = Bs + ((P) ^ 1) * 8192;                                           \
    if (t_ < 71) {                                                                        \
        _Pragma("unroll")                                                                 \
        for (int q = 0; q < 4; ++q) *(f32x4*)(Ax + dstE[q]) = ra[q];                      \
    }                                                                                     \
    short8 av[2][4], bv[2][4];                                                            \
    _Pragma("unroll")                                                                     \
    for (int kk = 0; kk < 2; ++kk)                                                        \
        _Pragma("unroll")                                                                 \
        for (int f = 0; f < 4; ++f)                                                       \
            av[kk][f] = *(const short8*)(Ac + ardB + f * 1024 + kk * 512);                \
    _Pragma("unroll")                                                                     \
    for (int kk = 0; kk < 2; ++kk)                                                        \
        _Pragma("unroll")                                                                 \
        for (int e = 0; e < 4; ++e)                                                       \
            bv[kk][e] = *(const short8*)(Bc + brdB + e * 1024 + kk * 512);                \
    const int tn_ = t_ + 2;                                                               \
    if (tn_ < 72) {                                                                       \
        const int jn = tn_ >> 3, cbn = tn_ & 7;                                           \
        const int aoffn = ((jn / 3) * WPAD + (jn % 3)) * CIN + cbn * 32;                  \
        _Pragma("unroll")                                                                 \
        for (int q = 0; q < 4; ++q)                                                       \
            ra[q] = *(const f32x4*)(Ab + abase[q] + aoffn);                               \
    }                                                                                     \
    _Pragma("unroll")                                                                     \
    for (int kk = 0; kk < 2; ++kk)                                                        \
        _Pragma("unroll")                                                                 \
        for (int f = 0; f < 4; ++f)                                                       \
            _Pragma("unroll")                                                             \
            for (int e = 0; e < 4; ++e)                                                   \
                acc[f][e] = __builtin_amdgcn_mfma_f32_32x32x16_bf16(av[kk][f], bv[kk][e], \
                                                                    acc[f][e], 0, 0, 0);  \
    if (t_ < 71) {                                                                        \
        _Pragma("unroll")                                                                 \
        for (int q = 0; q < 4; ++q) *(f32x4*)(Bx + dstE[q]) = rb[q];                      \
    }                                                                                     \
    if (tn_ < 72) {                                                                       \
        const int jn = tn_ >> 3, cbn = tn_ & 7;                                           \
        const int boffn = jn * 256 + cbn * 32;                                            \
        _Pragma("unroll")                                                                 \
        for (int q = 0; q < 4; ++q)                                                       \
            rb[q] = *(const f32x4*)(Wr + bbase[q] + boffn);                               \
    }                                                                                     \
    LGKM0();                                                                              \
    __builtin_amdgcn_s_barrier();                                                         \
} while (0)

__global__ __launch_bounds__(256, 2) void conv_gemm_kernel(const unsigned short* __restrict__ xq,
                                                           const unsigned short* __restrict__ Wr,
                                                           float* __restrict__ out,
                                                           float* __restrict__ sums)
{
    __shared__ __align__(16) unsigned short As[2 * 8192];   // 2 bufs x 16 KB
    __shared__ __align__(16) unsigned short Bs[2 * 8192];   // 2 bufs x 16 KB

    const int bid  = blockIdx.x;                    // 0..447
    const int blk  = (bid & 7) * 56 + (bid >> 3);   // bijective XCD swizzle (448 = 8*56)
    const int b    = blk / 14;
    const int m0   = (blk % 14) * 256;
    const int tid  = threadIdx.x;
    const int wv   = tid >> 6;          // 0..3
    const int lane = tid & 63;
    const int l31  = lane & 31;
    const int l5   = lane >> 5;
    const int wm   = wv >> 1;           // 0..1
    const int wn   = wv & 1;            // 0..1

    const unsigned short* Ab = xq + (size_t)b * (HP * WPAD * CIN);

    // ds-read element bases: + f*1024 + kk*512 (+ buf*8192) all immediate
    const int ardB = wm * 4096 + lane * 8;
    const int brdB = wn * 4096 + lane * 8;

    // staging: thread covers elems e = q*256+tid of each 8192-elem tile buffer;
    // e -> frag (g,kk,lane'): row = g*32+(lane'&31), k = kk*16+(lane'>>5)*8
    size_t abase[4], bbase[4];
    int    dstE[4];
#pragma unroll
    for (int q = 0; q < 4; ++q) {
        int e  = q * 256 + tid;
        int g  = e >> 7, kk = (e >> 6) & 1, ll = e & 63;
        int row = g * 32 + (ll & 31);
        int kc  = kk * 16 + (ll >> 5) * 8;
        abase[q] = (size_t)(m0 + row) * CIN + kc;
        bbase[q] = (size_t)row * KTOT + kc;
        dstE[q]  = e * 8;
    }

    f32x4 ra[4], rb[4];
    f32x16 acc[4][4];
#pragma unroll
    for (int f = 0; f < 4; ++f)
#pragma unroll
        for (int e = 0; e < 4; ++e)
#pragma unroll
            for (int r = 0; r < 16; ++r) acc[f][e][r] = 0.f;

    // prologue: tile0 -> buf0 (via regs); tile1 -> regs (written in iter 0)
#pragma unroll
    for (int q = 0; q < 4; ++q) ra[q] = *(const f32x4*)(Ab + abase[q] + 0);
#pragma unroll
    for (int q = 0; q < 4; ++q) rb[q] = *(const f32x4*)(Wr + bbase[q] + 0);
#pragma unroll
    for (int q = 0; q < 4; ++q) *(f32x4*)(As + dstE[q]) = ra[q];
#pragma unroll
    for (int q = 0; q < 4; ++q) *(f32x4*)(Bs + dstE[q]) = rb[q];
#pragma unroll
    for (int q = 0; q < 4; ++q) ra[q] = *(const f32x4*)(Ab + abase[q] + 32);  // tile1 A
#pragma unroll
    for (int q = 0; q < 4; ++q) rb[q] = *(const f32x4*)(Wr + bbase[q] + 32);  // tile1 B
    LGKM0();
    __builtin_amdgcn_s_barrier();

    for (int t = 0; t < 72; t += 2) {
        ITER(t, 0);
        ITER(t + 1, 1);
    }

    // epilogue: C/D col=lane&31 (n), row=(r&3)+8*(r>>2)+4*(lane>>5) (m).
    // w>=56 padding quads are exactly (mi odd && q==3). Fused BN stats.
#pragma unroll
    for (int ni = 0; ni < 4; ++ni) {
        const int n = wn * 128 + ni * 32 + l31;
        float s = 0.f, s2 = 0.f;
#pragma unroll
        for (int mi = 0; mi < 4; ++mi) {
#pragma unroll
            for (int q = 0; q < 4; ++q) {
                if ((mi & 1) && q == 3) continue;     // w = 56/60: padding
                const int m = m0 + wm * 128 + mi * 32 + q * 8 + l5 * 4;
                const int h = m >> 6, w = m & 63;
                f32x4 v = { acc[mi][ni][q * 4 + 0], acc[mi][ni][q * 4 + 1],
                            acc[mi][ni][q * 4 + 2], acc[mi][ni][q * 4 + 3] };
                s  += v[0] + v[1] + v[2] + v[3];
                s2 += v[0] * v[0] + v[1] * v[1] + v[2] * v[2] + v[3] * v[3];
                *reinterpret_cast<f32x4*>(&out[(((size_t)b * COUT + n) * HH + h) * WW + w]) = v;
            }
        }
        s  += __shfl_xor(s, 32);
        s2 += __shfl_xor(s2, 32);
        if (l5 == 0) {
            atomicAdd(&sums[n], s);
            atomicAdd(&sums[COUT + n], s2);
        }
    }
}

// ---------------- BN normalize + affine + ReLU (in place, f32x4) ----------------
__global__ void bn_apply_kernel(float* __restrict__ y, const float* __restrict__ sums,
                                const float* __restrict__ gamma, const float* __restrict__ beta)
{
    const int o = blockIdx.x, b = blockIdx.y;
    const float N = (float)(BATCH * HH * WW);
    const float mean = sums[o] / N;
    const float var  = sums[COUT + o] / N - mean * mean;
    const float inv  = 1.f / sqrtf(var + 1e-5f);
    const float a  = gamma[o] * inv;
    const float bb = beta[o] - mean * a;
    float* p = y + ((size_t)b * COUT + o) * (HH * WW);
    for (int i = threadIdx.x; i < 784; i += 256) {
        f32x4 v = *reinterpret_cast<const f32x4*>(p + i * 4);
#pragma unroll
        for (int r = 0; r < 4; ++r) v[r] = fmaxf(v[r] * a + bb, 0.f);
        *reinterpret_cast<f32x4*>(p + i * 4) = v;
    }
}

extern "C" void kernel_launch(void* const* d_in, const int* in_sizes, int n_in,
                              void* d_out, int out_size, void* d_ws, size_t ws_size,
                              hipStream_t stream)
{
    const float* x     = (const float*)d_in[0];
    const float* Wsrc  = (const float*)d_in[1];
    const float* gamma = (const float*)d_in[2];
    const float* beta  = (const float*)d_in[3];
    float* out = (float*)d_out;

    char* ws = (char*)d_ws;
    const size_t XQ_BYTES = (size_t)BATCH * HP * WPAD * CIN * 2;  // 62,914,560
    const size_t WR_BYTES = (size_t)COUT * KTOT * 2;              //  1,179,648
    unsigned short* xq = (unsigned short*)ws;
    unsigned short* wr = (unsigned short*)(ws + XQ_BYTES);
    float* sums = (float*)(ws + XQ_BYTES + WR_BYTES);

    hipMemsetAsync(sums, 0, 2 * COUT * sizeof(float), stream);

    zeropad_kernel<<<dim3(88, BATCH), 256, 0, stream>>>(xq);
    quant_kernel<<<dim3(HH, BATCH), 256, 0, stream>>>(x, xq);
    wrepack_kernel<<<(COUT * KTOT + 255) / 256, 256, 0, stream>>>(Wsrc, wr);

    conv_gemm_kernel<<<448, 256, 0, stream>>>(xq, wr, out, sums);

    bn_apply_kernel<<<dim3(COUT, BATCH), 256, 0, stream>>>(out, sums, gamma, beta);
}

// Round 7
// 543.916 us; speedup vs baseline: 5.4351x; 5.4351x over previous
//
#include <hip/hip_runtime.h>
#include <hip/hip_bf16.h>
#include <cstdint>
#include <cstddef>

#define BATCH 32
#define CIN   256
#define COUT  256
#define HH    56
#define WW    56
#define HP    60      // padded rows: 0..57 read; 58/59 slack (zeroed)
#define WPAD  64      // padded cols: 0,57 are conv zero-pad; 58..63 slack (zeroed)
#define KTOT  2304    // 9 * 256

typedef __attribute__((ext_vector_type(4)))  float f32x4;
typedef __attribute__((ext_vector_type(16))) float f32x16;
typedef __attribute__((ext_vector_type(8)))  short short8;

// ---------------- zero only the padding cells of xq (12.4 MB, not 63 MB) ----------------
__global__ void zeropad_kernel(unsigned short* __restrict__ xq)
{
    const int b   = blockIdx.y;
    const int idx = blockIdx.x * 256 + threadIdx.x;   // 0..22527
    const int pos = idx >> 5;
    const int ch  = (idx & 31) * 8;
    int hp, wp;
    if (pos < 256) {                     // rows {0,57,58,59} full
        int r = pos >> 6;
        hp = (r == 0) ? 0 : 56 + r;
        wp = pos & 63;
    } else {                             // rows 1..56, cols {0,57..63}
        int i2 = pos - 256;
        int c  = i2 & 7;
        hp = (i2 >> 3) + 1;
        wp = (c == 0) ? 0 : 56 + c;
    }
    short8 z = {0, 0, 0, 0, 0, 0, 0, 0};
    *reinterpret_cast<short8*>(xq + (((size_t)b * HP + hp) * WPAD + wp) * CIN + ch) = z;
}

// ---------------- BFP quantize + NCHW->padded-NHWC bf16 repack ----------------
__global__ void quant_kernel(const float* __restrict__ x, unsigned short* __restrict__ xq)
{
    const int h   = blockIdx.x;       // 0..55
    const int b   = blockIdx.y;       // 0..31
    const int tid = threadIdx.x;
    const int wv  = tid >> 6;
    const int w   = tid & 63;
    if (w >= WW) return;
    for (int cb = wv; cb < 8; cb += 4) {
        float v[32];
        float mx = 0.f;
        const float* xp = x + (((size_t)b * CIN + cb * 32) * HH + h) * WW + w;
#pragma unroll
        for (int c = 0; c < 32; ++c) {
            float t = xp[(size_t)c * HH * WW];
            v[c] = t;
            mx = fmaxf(mx, fabsf(t));
        }
        float m = fmaxf(mx, 1e-12f);
        int e;
        frexpf(m, &e);
        e -= 1;                                  // exact floor(log2(m))
        e = (e < -64) ? -64 : ((e > 63) ? 63 : e);
        float step = exp2f((float)(e - 7));
        float inv  = exp2f((float)(7 - e));
        unsigned short qb[32];
#pragma unroll
        for (int c = 0; c < 32; ++c) {
            float q = rintf(v[c] * inv);          // round-half-even, matches jnp.round
            q = fminf(fmaxf(q, -128.f), 127.f);
            float val = q * step;                 // exactly representable in bf16
            __hip_bfloat16 bv = __float2bfloat16(val);
            qb[c] = *reinterpret_cast<unsigned short*>(&bv);
        }
        unsigned short* dst = xq + (((size_t)b * HP + (h + 1)) * WPAD + (w + 1)) * CIN + cb * 32;
#pragma unroll
        for (int i = 0; i < 4; ++i)
            *reinterpret_cast<short8*>(dst + i * 8) = *reinterpret_cast<const short8*>(qb + i * 8);
    }
}

// ---------------- weight repack: OIHW fp32 -> [n][j=kh*3+kw][c] bf16 ----------------
__global__ void wrepack_kernel(const float* __restrict__ Wsrc, unsigned short* __restrict__ Wr)
{
    int idx = blockIdx.x * 256 + threadIdx.x;
    if (idx >= COUT * KTOT) return;
    int n = idx / KTOT;
    int r = idx % KTOT;
    int j = r >> 8;    // 0..8
    int c = r & 255;
    float val = Wsrc[((size_t)n * CIN + c) * 9 + j];
    __hip_bfloat16 bv = __float2bfloat16(val);
    Wr[idx] = *reinterpret_cast<unsigned short*>(&bv);
}

// ---------------- implicit-GEMM conv: 4 waves x (128x128), BARRIER-FREE ----------------
// Each wave owns a PRIVATE 32 KB LDS region (2 bufs x [A 4096 | B 4096] elems)
// and its own staging; the only sync is the wave's own counted vmcnt(16).
// No s_barrier / sched_barrier / lgkm asm in the K-loop: waves drift freely
// (independent phases per SIMD), and the compiler may interleave ds_read /
// stage-issue / MFMA inside the straight-line body.
//   iter t (buf P = t&1): issue 16 gload_lds (tile t+1 -> buf P^1);
//     vmcnt(16)  [= tile t's 16 loads landed; t+1's remain in flight];
//     16x ds_read_b128 frags of tile t; 32x MFMA 32x32x16.
//   RAW: vmcnt(16).  WAR: buf P^1's ds_reads (iter t-1) completed before
//   their MFMAs consumed them, which precede iter t in program order.
// LDS fragment-order: frag f (A: f=mi*2+kk, B: f=ni*2+kk) = 512 elems; lane l
// at elem f*512+l*8 (byte l*16) -> conflict-free reads AND linear DMA dest.
// A/B frag source (32x32x16): row/col = base+32*idx+(l&31), k = kk*16+(l>>5)*8.
__device__ __forceinline__ void gload_lds16(const void* g, void* l)
{
    __builtin_amdgcn_global_load_lds((const __attribute__((address_space(1))) void*)g,
                                     (__attribute__((address_space(3))) void*)l, 16, 0, 0);
}
#define VMWAIT(n) do { asm volatile("s_waitcnt vmcnt(" #n ")" ::: "memory"); } while (0)

#define ITER(T, P) do {                                                                   \
    const int t_  = (T);                                                                  \
    const int tn_ = t_ + 1;                                                               \
    const unsigned short* Aw = Wbase + (P) * 8192;                                        \
    const unsigned short* Bw = Wbase + (P) * 8192 + 4096;                                 \
    unsigned short*       Ax = Wbase + ((P) ^ 1) * 8192;                                  \
    if (tn_ < 72) {                                                                       \
        const int jn  = tn_ >> 3, cbn = tn_ & 7;                                          \
        const int khn = jn / 3,   kwn = jn - 3 * khn;                                     \
        const int aoff = (khn * WPAD + kwn) * CIN + cbn * 32;                             \
        const int boff = jn * 256 + cbn * 32;                                             \
        _Pragma("unroll")                                                                 \
        for (int q = 0; q < 8; ++q)                                                       \
            gload_lds16(Ab + aRowI[q] + aoff, (void*)(Ax + q * 512));                     \
        _Pragma("unroll")                                                                 \
        for (int q = 0; q < 8; ++q)                                                       \
            gload_lds16(Wr + bRowI[q] + boff, (void*)(Ax + 4096 + q * 512));              \
        VMWAIT(16);                                                                       \
    } else {                                                                              \
        VMWAIT(0);                                                                        \
    }                                                                                     \
    short8 av[2][4], bv[2][4];                                                            \
    _Pragma("unroll")                                                                     \
    for (int mi = 0; mi < 4; ++mi)                                                        \
        _Pragma("unroll")                                                                 \
        for (int kk = 0; kk < 2; ++kk)                                                    \
            av[kk][mi] = *(const short8*)(Aw + (mi * 2 + kk) * 512 + lane * 8);           \
    _Pragma("unroll")                                                                     \
    for (int ni = 0; ni < 4; ++ni)                                                        \
        _Pragma("unroll")                                                                 \
        for (int kk = 0; kk < 2; ++kk)                                                    \
            bv[kk][ni] = *(const short8*)(Bw + (ni * 2 + kk) * 512 + lane * 8);           \
    _Pragma("unroll")                                                                     \
    for (int kk = 0; kk < 2; ++kk)                                                        \
        _Pragma("unroll")                                                                 \
        for (int mi = 0; mi < 4; ++mi)                                                    \
            _Pragma("unroll")                                                             \
            for (int ni = 0; ni < 4; ++ni)                                                \
                acc[mi][ni] = __builtin_amdgcn_mfma_f32_32x32x16_bf16(av[kk][mi],         \
                                    bv[kk][ni], acc[mi][ni], 0, 0, 0);                    \
} while (0)

__global__ __launch_bounds__(256, 1) void conv_gemm_kernel(const unsigned short* __restrict__ xq,
                                                           const unsigned short* __restrict__ Wr,
                                                           float* __restrict__ out,
                                                           float* __restrict__ sums)
{
    extern __shared__ __align__(16) unsigned short lds[];   // 4 waves x 16384 elems

    const int bid  = blockIdx.x;                    // 0..447
    const int blk  = (bid & 7) * 56 + (bid >> 3);   // bijective XCD swizzle (448 = 8*56)
    const int b    = blk / 14;
    const int m0   = (blk % 14) * 256;
    const int tid  = threadIdx.x;
    const int wv   = tid >> 6;          // 0..3
    const int lane = tid & 63;
    const int l31  = lane & 31;
    const int l5   = lane >> 5;
    const int wm   = wv >> 1;           // 0..1
    const int wn   = wv & 1;            // 0..1

    const unsigned short* Ab = xq + (size_t)b * (HP * WPAD * CIN);
    unsigned short* Wbase = lds + wv * 16384;       // private 32 KB region

    // per-lane invariant source offsets (elements); frag q covers rows 32*(q>>1)..+31,
    // k-half q&1:  row = base + (q>>1)*32 + (l&31), k = (q&1)*16 + (l>>5)*8
    int aRowI[8], bRowI[8];
#pragma unroll
    for (int q = 0; q < 8; ++q) {
        const int kc = (q & 1) * 16 + l5 * 8;
        aRowI[q] = (m0 + wm * 128 + (q >> 1) * 32 + l31) * CIN + kc;
        bRowI[q] = (wn * 128 + (q >> 1) * 32 + l31) * KTOT + kc;
    }

    f32x16 acc[4][4];
#pragma unroll
    for (int f = 0; f < 4; ++f)
#pragma unroll
        for (int e = 0; e < 4; ++e)
#pragma unroll
            for (int r = 0; r < 16; ++r) acc[f][e][r] = 0.f;

    // prologue: stage tile 0 (j=0, cb=0) into buf 0
#pragma unroll
    for (int q = 0; q < 8; ++q)
        gload_lds16(Ab + aRowI[q], (void*)(Wbase + q * 512));
#pragma unroll
    for (int q = 0; q < 8; ++q)
        gload_lds16(Wr + bRowI[q], (void*)(Wbase + 4096 + q * 512));

    for (int t = 0; t < 72; t += 2) {
        ITER(t, 0);
        ITER(t + 1, 1);
    }

    // epilogue: C/D col=lane&31 (n), row=(r&3)+8*(r>>2)+4*(lane>>5) (m).
    // w>=56 padding quads are exactly (mi odd && qq==3). Fused BN stats.
#pragma unroll
    for (int ni = 0; ni < 4; ++ni) {
        const int n = wn * 128 + ni * 32 + l31;
        float s = 0.f, s2 = 0.f;
#pragma unroll
        for (int mi = 0; mi < 4; ++mi) {
#pragma unroll
            for (int qq = 0; qq < 4; ++qq) {
                if ((mi & 1) && qq == 3) continue;     // w = 56/60: padding
                const int m = m0 + wm * 128 + mi * 32 + qq * 8 + l5 * 4;
                const int h = m >> 6, w = m & 63;
                f32x4 v = { acc[mi][ni][qq * 4 + 0], acc[mi][ni][qq * 4 + 1],
                            acc[mi][ni][qq * 4 + 2], acc[mi][ni][qq * 4 + 3] };
                s  += v[0] + v[1] + v[2] + v[3];
                s2 += v[0] * v[0] + v[1] * v[1] + v[2] * v[2] + v[3] * v[3];
                *reinterpret_cast<f32x4*>(&out[(((size_t)b * COUT + n) * HH + h) * WW + w]) = v;
            }
        }
        s  += __shfl_xor(s, 32);
        s2 += __shfl_xor(s2, 32);
        if (l5 == 0) {
            atomicAdd(&sums[n], s);
            atomicAdd(&sums[COUT + n], s2);
        }
    }
}

// ---------------- BN normalize + affine + ReLU (in place, f32x4) ----------------
__global__ void bn_apply_kernel(float* __restrict__ y, const float* __restrict__ sums,
                                const float* __restrict__ gamma, const float* __restrict__ beta)
{
    const int o = blockIdx.x, b = blockIdx.y;
    const float N = (float)(BATCH * HH * WW);
    const float mean = sums[o] / N;
    const float var  = sums[COUT + o] / N - mean * mean;
    const float inv  = 1.f / sqrtf(var + 1e-5f);
    const float a  = gamma[o] * inv;
    const float bb = beta[o] - mean * a;
    float* p = y + ((size_t)b * COUT + o) * (HH * WW);
    for (int i = threadIdx.x; i < 784; i += 256) {
        f32x4 v = *reinterpret_cast<const f32x4*>(p + i * 4);
#pragma unroll
        for (int r = 0; r < 4; ++r) v[r] = fmaxf(v[r] * a + bb, 0.f);
        *reinterpret_cast<f32x4*>(p + i * 4) = v;
    }
}

extern "C" void kernel_launch(void* const* d_in, const int* in_sizes, int n_in,
                              void* d_out, int out_size, void* d_ws, size_t ws_size,
                              hipStream_t stream)
{
    const float* x     = (const float*)d_in[0];
    const float* Wsrc  = (const float*)d_in[1];
    const float* gamma = (const float*)d_in[2];
    const float* beta  = (const float*)d_in[3];
    float* out = (float*)d_out;

    char* ws = (char*)d_ws;
    const size_t XQ_BYTES = (size_t)BATCH * HP * WPAD * CIN * 2;  // 62,914,560
    const size_t WR_BYTES = (size_t)COUT * KTOT * 2;              //  1,179,648
    unsigned short* xq = (unsigned short*)ws;
    unsigned short* wr = (unsigned short*)(ws + XQ_BYTES);
    float* sums = (float*)(ws + XQ_BYTES + WR_BYTES);

    hipMemsetAsync(sums, 0, 2 * COUT * sizeof(float), stream);

    zeropad_kernel<<<dim3(88, BATCH), 256, 0, stream>>>(xq);
    quant_kernel<<<dim3(HH, BATCH), 256, 0, stream>>>(x, xq);
    wrepack_kernel<<<(COUT * KTOT + 255) / 256, 256, 0, stream>>>(Wsrc, wr);

    hipFuncSetAttribute(reinterpret_cast<const void*>(&conv_gemm_kernel),
                        hipFuncAttributeMaxDynamicSharedMemorySize, 131072);
    conv_gemm_kernel<<<448, 256, 131072, stream>>>(xq, wr, out, sums);

    bn_apply_kernel<<<dim3(COUT, BATCH), 256, 0, stream>>>(out, sums, gamma, beta);
}

// Round 8
// 243.701 us; speedup vs baseline: 12.1306x; 2.2319x over previous
//
#include <hip/hip_runtime.h>
#include <hip/hip_bf16.h>
#include <cstdint>
#include <cstddef>

#define BATCH 32
#define CIN   256
#define COUT  256
#define HH    56
#define WW    56
#define HP    60      // padded rows: 0..57 read; 58/59 slack (zeroed)
#define WPAD  64      // padded cols: 0,57 are conv zero-pad; 58..63 slack (zeroed)
#define KTOT  2304    // 9 * 256

typedef __attribute__((ext_vector_type(4))) float f32x4;
typedef __attribute__((ext_vector_type(8))) short short8;

// ---------------- zero only the padding cells of xq (12.4 MB, not 63 MB) ----------------
__global__ void zeropad_kernel(unsigned short* __restrict__ xq)
{
    const int b   = blockIdx.y;
    const int idx = blockIdx.x * 256 + threadIdx.x;   // 0..22527
    const int pos = idx >> 5;
    const int ch  = (idx & 31) * 8;
    int hp, wp;
    if (pos < 256) {                     // rows {0,57,58,59} full
        int r = pos >> 6;
        hp = (r == 0) ? 0 : 56 + r;
        wp = pos & 63;
    } else {                             // rows 1..56, cols {0,57..63}
        int i2 = pos - 256;
        int c  = i2 & 7;
        hp = (i2 >> 3) + 1;
        wp = (c == 0) ? 0 : 56 + c;
    }
    short8 z = {0, 0, 0, 0, 0, 0, 0, 0};
    *reinterpret_cast<short8*>(xq + (((size_t)b * HP + hp) * WPAD + wp) * CIN + ch) = z;
}

// ---------------- BFP quantize + NCHW->padded-NHWC bf16 repack ----------------
__global__ void quant_kernel(const float* __restrict__ x, unsigned short* __restrict__ xq)
{
    const int h   = blockIdx.x;       // 0..55
    const int b   = blockIdx.y;       // 0..31
    const int tid = threadIdx.x;
    const int wv  = tid >> 6;
    const int w   = tid & 63;
    if (w >= WW) return;
    for (int cb = wv; cb < 8; cb += 4) {
        float v[32];
        float mx = 0.f;
        const float* xp = x + (((size_t)b * CIN + cb * 32) * HH + h) * WW + w;
#pragma unroll
        for (int c = 0; c < 32; ++c) {
            float t = xp[(size_t)c * HH * WW];
            v[c] = t;
            mx = fmaxf(mx, fabsf(t));
        }
        float m = fmaxf(mx, 1e-12f);
        int e;
        frexpf(m, &e);
        e -= 1;                                  // exact floor(log2(m))
        e = (e < -64) ? -64 : ((e > 63) ? 63 : e);
        float step = exp2f((float)(e - 7));
        float inv  = exp2f((float)(7 - e));
        unsigned short qb[32];
#pragma unroll
        for (int c = 0; c < 32; ++c) {
            float q = rintf(v[c] * inv);          // round-half-even, matches jnp.round
            q = fminf(fmaxf(q, -128.f), 127.f);
            float val = q * step;                 // exactly representable in bf16
            __hip_bfloat16 bv = __float2bfloat16(val);
            qb[c] = *reinterpret_cast<unsigned short*>(&bv);
        }
        unsigned short* dst = xq + (((size_t)b * HP + (h + 1)) * WPAD + (w + 1)) * CIN + cb * 32;
#pragma unroll
        for (int i = 0; i < 4; ++i)
            *reinterpret_cast<short8*>(dst + i * 8) = *reinterpret_cast<const short8*>(qb + i * 8);
    }
}

// ---------------- weight repack: OIHW fp32 -> [n][j=kh*3+kw][c] bf16 ----------------
__global__ void wrepack_kernel(const float* __restrict__ Wsrc, unsigned short* __restrict__ Wr)
{
    int idx = blockIdx.x * 256 + threadIdx.x;
    if (idx >= COUT * KTOT) return;
    int n = idx / KTOT;
    int r = idx % KTOT;
    int j = r >> 8;    // 0..8
    int c = r & 255;
    float val = Wsrc[((size_t)n * CIN + c) * 9 + j];
    __hip_bfloat16 bv = __float2bfloat16(val);
    Wr[idx] = *reinterpret_cast<unsigned short*>(&bv);
}

// ======================= implicit-GEMM conv — 8-phase template port =======================
// 256x256 tile, BK=64, 8 waves (2M x 4N), per-wave 128x64 out, 16x16x32 MFMA.
// LDS: A 3-deep (3 x 32 KB) + B 2-deep (2 x 32 KB) = 160 KB exactly.
// Per K-tile kt: 4 phases, each { ds_read 4 A-frags (+8 B-frags in ph0) ||
//   stage ONE half-tile (2 gload_lds/thread) -> s_barrier -> setprio(1) ->
//   16 MFMA -> setprio(0) -> [ph3: counted VMWAIT] -> s_barrier }.
// Stage stream: p0->B1(kt+1), p1->B2(kt+1), p2->A1(kt+2), p3->A2(kt+2).
// VMWAIT(4) at kt end: drains A(kt+1)[staged kt-1] + B(kt+1); leaves A(kt+2) in
// flight. 3-deep A makes the counted (non-zero) wait possible; buffer rotation
// A: kt%3, B: kt%2 gives WAR safety (write target never equals read buffer).
// LDS fragment-order layout (verified r3/r4, 0 bank conflicts): frag (grp,kk) =
// 16 rows x 32 k = 512 elem; lane l at elem l*8 (byte l*16); DMA dest linear,
// global source pre-swizzled (row=l&15, kchunk=l>>4).
__device__ __forceinline__ void gload_lds16(const void* g, void* l)
{
    __builtin_amdgcn_global_load_lds((const __attribute__((address_space(1))) void*)g,
                                     (__attribute__((address_space(3))) void*)l, 16, 0, 0);
}
#define VMWAIT(n) do { asm volatile("s_waitcnt vmcnt(" #n ")" ::: "memory"); } while (0)
#define PRIO(n)   __builtin_amdgcn_s_setprio(n)
#define SBAR()    __builtin_amdgcn_s_barrier()

// 16 MFMA for m-groups {2p, 2p+1}
#define MFMA_PH(p)                                                                        \
    _Pragma("unroll")                                                                     \
    for (int kk = 0; kk < 2; ++kk)                                                        \
        _Pragma("unroll")                                                                 \
        for (int jj = 0; jj < 2; ++jj)                                                    \
            _Pragma("unroll")                                                             \
            for (int ni = 0; ni < 4; ++ni)                                                \
                acc[2 * (p) + jj][ni] = __builtin_amdgcn_mfma_f32_16x16x32_bf16(          \
                    afv[jj][kk], bfv[ni][kk], acc[2 * (p) + jj][ni], 0, 0, 0);

#define LDA_PH(p)                                                                         \
    _Pragma("unroll")                                                                     \
    for (int jj = 0; jj < 2; ++jj)                                                        \
        _Pragma("unroll")                                                                 \
        for (int kk = 0; kk < 2; ++kk)                                                    \
            afv[jj][kk] = *(const short8*)(Ac + (wm * 8 + 2 * (p) + jj) * 1024 +          \
                                           kk * 512 + lane * 8);

// KT: one K-tile. A3/B2: read bufs (kt%3, kt%2); SB/SA: stage enables;
// A3n/B2n: stage target bufs ((kt+2)%3, (kt+1)%2); VMT: tail waitcnt.
#define KT(ktE, A3, B2, SB, SA, A3n, B2n, VMT) do {                                       \
    const int kt_ = (ktE);                                                                \
    const unsigned short* Ac = lds + (A3) * 16384;                                        \
    const unsigned short* Bc = lds + 49152 + (B2) * 16384;                                \
    short8 bfv[4][2], afv[2][2];                                                          \
    /* ---- phase 0 ---- */                                                               \
    _Pragma("unroll")                                                                     \
    for (int ni = 0; ni < 4; ++ni)                                                        \
        _Pragma("unroll")                                                                 \
        for (int kk = 0; kk < 2; ++kk)                                                    \
            bfv[ni][kk] = *(const short8*)(Bc + (wn * 4 + ni) * 1024 + kk * 512 +         \
                                           lane * 8);                                     \
    LDA_PH(0);                                                                            \
    if (SB) stgB(kt_ + 1, 0, (B2n));                                                      \
    SBAR(); PRIO(1); MFMA_PH(0); PRIO(0); SBAR();                                         \
    /* ---- phase 1 ---- */                                                               \
    LDA_PH(1);                                                                            \
    if (SB) stgB(kt_ + 1, 1, (B2n));                                                      \
    SBAR(); PRIO(1); MFMA_PH(1); PRIO(0); SBAR();                                         \
    /* ---- phase 2 ---- */                                                               \
    LDA_PH(2);                                                                            \
    if (SA) stgA(kt_ + 2, 0, (A3n));                                                      \
    SBAR(); PRIO(1); MFMA_PH(2); PRIO(0); SBAR();                                         \
    /* ---- phase 3 ---- */                                                               \
    LDA_PH(3);                                                                            \
    if (SA) stgA(kt_ + 2, 1, (A3n));                                                      \
    SBAR(); PRIO(1); MFMA_PH(3); PRIO(0);                                                 \
    VMT;                                                                                  \
    SBAR();                                                                               \
} while (0)

__global__ __launch_bounds__(512) void conv_gemm_kernel(const unsigned short* __restrict__ xq,
                                                        const unsigned short* __restrict__ Wr,
                                                        float* __restrict__ out,
                                                        float* __restrict__ sums)
{
    extern __shared__ __align__(16) unsigned short lds[];   // A: 3x16384, B: 2x16384 elems

    const int bid  = blockIdx.x;                    // 0..447
    const int blk  = (bid & 7) * 56 + (bid >> 3);   // bijective XCD swizzle (448 = 8*56)
    const int b    = blk / 14;
    const int m0   = (blk % 14) * 256;
    const int tid  = threadIdx.x;
    const int wv   = tid >> 6;          // 0..7
    const int lane = tid & 63;
    const int ln   = lane & 15;
    const int kg   = lane >> 4;         // 0..3
    const int wm   = wv >> 2;           // 0..1  (M half)
    const int wn   = wv & 3;            // 0..3  (N quarter)

    const unsigned short* Ab = xq + (size_t)b * (HP * WPAD * CIN);

    // pre-swizzled per-lane source offsets (fragment order)
    const int aLane = ln * CIN  + kg * 8;
    const int bLane = ln * KTOT + kg * 8;

    // stage one half-tile (h=0/1) of A for K-tile kt2 into buf a3 (2 loads/thread)
    auto stgA = [&](int kt2, int h, int a3) {
        const int j  = kt2 >> 2;
        const int kh = j / 3, kw = j - 3 * kh;
        const int aoff = (kh * WPAD + kw) * CIN + (kt2 & 3) * 64;
        unsigned short* dst = lds + a3 * 16384;
#pragma unroll
        for (int q = 0; q < 2; ++q) {
            const int slot = wv * 2 + q;                 // 0..15
            const int tg   = h * 8 + (slot >> 1);        // tile row-group
            const int kk   = slot & 1;
            gload_lds16(Ab + (size_t)(m0 + tg * 16) * CIN + aoff + kk * 32 + aLane,
                        (void*)(dst + tg * 1024 + kk * 512));
        }
    };
    auto stgB = [&](int kt1, int h, int b2) {
        const int boff = (kt1 >> 2) * 256 + (kt1 & 3) * 64;
        unsigned short* dst = lds + 49152 + b2 * 16384;
#pragma unroll
        for (int q = 0; q < 2; ++q) {
            const int slot = wv * 2 + q;
            const int tg   = h * 8 + (slot >> 1);
            const int kk   = slot & 1;
            gload_lds16(Wr + (size_t)(tg * 16) * KTOT + boff + kk * 32 + bLane,
                        (void*)(dst + tg * 1024 + kk * 512));
        }
    };

    f32x4 acc[8][4];
#pragma unroll
    for (int i = 0; i < 8; ++i)
#pragma unroll
        for (int jn = 0; jn < 4; ++jn) acc[i][jn] = (f32x4){0.f, 0.f, 0.f, 0.f};

    // prologue: A(0), A(1), B(0) fully staged (12 loads/thread)
    stgA(0, 0, 0); stgA(0, 1, 0);
    stgA(1, 0, 1); stgA(1, 1, 1);
    stgB(0, 0, 0); stgB(0, 1, 0);
    VMWAIT(0);
    SBAR();

    for (int it = 0; it < 5; ++it) {
        const int k0 = it * 6;
        KT(k0 + 0, 0, 0, 1, 1, 2, 1, VMWAIT(4));
        KT(k0 + 1, 1, 1, 1, 1, 0, 0, VMWAIT(4));
        KT(k0 + 2, 2, 0, 1, 1, 1, 1, VMWAIT(4));
        KT(k0 + 3, 0, 1, 1, 1, 2, 0, VMWAIT(4));
        KT(k0 + 4, 1, 0, 1, 1, 0, 1, VMWAIT(4));
        KT(k0 + 5, 2, 1, 1, 1, 1, 0, VMWAIT(4));
    }
    KT(30, 0, 0, 1, 1, 2, 1, VMWAIT(4));
    KT(31, 1, 1, 1, 1, 0, 0, VMWAIT(4));
    KT(32, 2, 0, 1, 1, 1, 1, VMWAIT(4));
    KT(33, 0, 1, 1, 1, 2, 0, VMWAIT(4));
    KT(34, 1, 0, 1, 0, 0, 1, VMWAIT(0));   // stages B(35) only; drain all
    KT(35, 2, 1, 0, 0, 0, 0, (void)0);     // no staging

    // epilogue (verified r2-r4): C/D col=lane&15 (n), row=(lane>>4)*4+reg (m);
    // w<56 mask == !(i%4==3 && kg>=2); fused BN stats via shfl + atomicAdd.
#pragma unroll
    for (int jn = 0; jn < 4; ++jn) {
        const int n = wn * 64 + jn * 16 + ln;
        float s = 0.f, s2 = 0.f;
#pragma unroll
        for (int i = 0; i < 8; ++i) {
            if ((i & 3) == 3 && kg >= 2) continue;   // w = 56..63: padding lanes
            const int mm = m0 + wm * 128 + i * 16 + kg * 4;
            const int h = mm >> 6, w = mm & 63;
            f32x4 v = acc[i][jn];
            s  += v[0] + v[1] + v[2] + v[3];
            s2 += v[0] * v[0] + v[1] * v[1] + v[2] * v[2] + v[3] * v[3];
            *reinterpret_cast<f32x4*>(&out[(((size_t)b * COUT + n) * HH + h) * WW + w]) = v;
        }
        s  += __shfl_xor(s, 16);  s  += __shfl_xor(s, 32);
        s2 += __shfl_xor(s2, 16); s2 += __shfl_xor(s2, 32);
        if (kg == 0) {
            atomicAdd(&sums[n], s);
            atomicAdd(&sums[COUT + n], s2);
        }
    }
}

// ---------------- BN normalize + affine + ReLU (in place, f32x4) ----------------
__global__ void bn_apply_kernel(float* __restrict__ y, const float* __restrict__ sums,
                                const float* __restrict__ gamma, const float* __restrict__ beta)
{
    const int o = blockIdx.x, b = blockIdx.y;
    const float N = (float)(BATCH * HH * WW);
    const float mean = sums[o] / N;
    const float var  = sums[COUT + o] / N - mean * mean;
    const float inv  = 1.f / sqrtf(var + 1e-5f);
    const float a  = gamma[o] * inv;
    const float bb = beta[o] - mean * a;
    float* p = y + ((size_t)b * COUT + o) * (HH * WW);
    for (int i = threadIdx.x; i < 784; i += 256) {
        f32x4 v = *reinterpret_cast<const f32x4*>(p + i * 4);
#pragma unroll
        for (int r = 0; r < 4; ++r) v[r] = fmaxf(v[r] * a + bb, 0.f);
        *reinterpret_cast<f32x4*>(p + i * 4) = v;
    }
}

extern "C" void kernel_launch(void* const* d_in, const int* in_sizes, int n_in,
                              void* d_out, int out_size, void* d_ws, size_t ws_size,
                              hipStream_t stream)
{
    const float* x     = (const float*)d_in[0];
    const float* Wsrc  = (const float*)d_in[1];
    const float* gamma = (const float*)d_in[2];
    const float* beta  = (const float*)d_in[3];
    float* out = (float*)d_out;

    char* ws = (char*)d_ws;
    const size_t XQ_BYTES = (size_t)BATCH * HP * WPAD * CIN * 2;  // 62,914,560
    const size_t WR_BYTES = (size_t)COUT * KTOT * 2;              //  1,179,648
    unsigned short* xq = (unsigned short*)ws;
    unsigned short* wr = (unsigned short*)(ws + XQ_BYTES);
    float* sums = (float*)(ws + XQ_BYTES + WR_BYTES);

    hipMemsetAsync(sums, 0, 2 * COUT * sizeof(float), stream);

    zeropad_kernel<<<dim3(88, BATCH), 256, 0, stream>>>(xq);
    quant_kernel<<<dim3(HH, BATCH), 256, 0, stream>>>(x, xq);
    wrepack_kernel<<<(COUT * KTOT + 255) / 256, 256, 0, stream>>>(Wsrc, wr);

    hipFuncSetAttribute(reinterpret_cast<const void*>(&conv_gemm_kernel),
                        hipFuncAttributeMaxDynamicSharedMemorySize, 163840);
    conv_gemm_kernel<<<448, 512, 163840, stream>>>(xq, wr, out, sums);

    bn_apply_kernel<<<dim3(COUT, BATCH), 256, 0, stream>>>(out, sums, gamma, beta);
}

// Round 9
// 210.901 us; speedup vs baseline: 14.0172x; 1.1555x over previous
//
#include <hip/hip_runtime.h>
#include <hip/hip_bf16.h>
#include <cstdint>
#include <cstddef>

#define BATCH 32
#define CIN   256
#define COUT  256
#define HH    56
#define WW    56
#define HP    60      // padded rows: 0..57 read; 58/59 slack (zeroed)
#define WPAD  64      // padded cols: 0,57 are conv zero-pad; 58..63 slack (zeroed)
#define KTOT  2304    // 9 * 256
#define MTOT  100352  // 32 * 56 * 56 real output rows
#define HW    3136    // 56*56
#define NBLK  392     // MTOT / 256 (= 8 * 49)

typedef __attribute__((ext_vector_type(4))) float f32x4;
typedef __attribute__((ext_vector_type(8))) short short8;

// ---------------- zero only the padding cells of xq (12.4 MB, not 63 MB) ----------------
__global__ void zeropad_kernel(unsigned short* __restrict__ xq)
{
    const int b   = blockIdx.y;
    const int idx = blockIdx.x * 256 + threadIdx.x;   // 0..22527
    const int pos = idx >> 5;
    const int ch  = (idx & 31) * 8;
    int hp, wp;
    if (pos < 256) {                     // rows {0,57,58,59} full
        int r = pos >> 6;
        hp = (r == 0) ? 0 : 56 + r;
        wp = pos & 63;
    } else {                             // rows 1..56, cols {0,57..63}
        int i2 = pos - 256;
        int c  = i2 & 7;
        hp = (i2 >> 3) + 1;
        wp = (c == 0) ? 0 : 56 + c;
    }
    short8 z = {0, 0, 0, 0, 0, 0, 0, 0};
    *reinterpret_cast<short8*>(xq + (((size_t)b * HP + hp) * WPAD + wp) * CIN + ch) = z;
}

// ---------------- BFP quantize + NCHW->padded-NHWC bf16 repack ----------------
__global__ void quant_kernel(const float* __restrict__ x, unsigned short* __restrict__ xq)
{
    const int h   = blockIdx.x;       // 0..55
    const int b   = blockIdx.y;       // 0..31
    const int tid = threadIdx.x;
    const int wv  = tid >> 6;
    const int w   = tid & 63;
    if (w >= WW) return;
    for (int cb = wv; cb < 8; cb += 4) {
        float v[32];
        float mx = 0.f;
        const float* xp = x + (((size_t)b * CIN + cb * 32) * HH + h) * WW + w;
#pragma unroll
        for (int c = 0; c < 32; ++c) {
            float t = xp[(size_t)c * HH * WW];
            v[c] = t;
            mx = fmaxf(mx, fabsf(t));
        }
        float m = fmaxf(mx, 1e-12f);
        int e;
        frexpf(m, &e);
        e -= 1;                                  // exact floor(log2(m))
        e = (e < -64) ? -64 : ((e > 63) ? 63 : e);
        float step = exp2f((float)(e - 7));
        float inv  = exp2f((float)(7 - e));
        unsigned short qb[32];
#pragma unroll
        for (int c = 0; c < 32; ++c) {
            float q = rintf(v[c] * inv);          // round-half-even, matches jnp.round
            q = fminf(fmaxf(q, -128.f), 127.f);
            float val = q * step;                 // exactly representable in bf16
            __hip_bfloat16 bv = __float2bfloat16(val);
            qb[c] = *reinterpret_cast<unsigned short*>(&bv);
        }
        unsigned short* dst = xq + (((size_t)b * HP + (h + 1)) * WPAD + (w + 1)) * CIN + cb * 32;
#pragma unroll
        for (int i = 0; i < 4; ++i)
            *reinterpret_cast<short8*>(dst + i * 8) = *reinterpret_cast<const short8*>(qb + i * 8);
    }
}

// ------- weight repack: OIHW fp32 -> DMA-ready per-K-tile LDS image (bf16) -------
// WrP[kt][tg][kk][l][i]: elem E = kt*16384 + tg*1024 + kk*512 + l*8 + i maps to
// n = tg*16 + (l&15), c = (kt&3)*64 + kk*32 + (l>>4)*8 + i, j = kt>>2.
// Conv stages B with fully CONTIGUOUS 1 KB global_load_lds streams.
__global__ void wrepack_kernel(const float* __restrict__ Wsrc, unsigned short* __restrict__ WrP)
{
    int E = blockIdx.x * 256 + threadIdx.x;
    if (E >= 36 * 16384) return;       // 589,824 = COUT*KTOT
    int kt = E >> 14;
    int r  = E & 16383;
    int tg = r >> 10;
    int kk = (r >> 9) & 1;
    int l  = (r >> 3) & 63;
    int i  = E & 7;
    int n  = tg * 16 + (l & 15);
    int c  = (kt & 3) * 64 + kk * 32 + (l >> 4) * 8 + i;
    int j  = kt >> 2;
    float val = Wsrc[((size_t)n * CIN + c) * 9 + j];
    __hip_bfloat16 bv = __float2bfloat16(val);
    WrP[E] = *reinterpret_cast<unsigned short*>(&bv);
}

// ======================= implicit-GEMM conv — 8-phase, REAL-M (no padding waste) =====
// 256x256 tile over M = 100,352 REAL output rows (m = b*3136 + h*56 + w), 392 blocks.
// Address layout decoupled from GEMM row index: per-lane row bases (2 ints) map
// row -> padded xq offset; taps remain uniform scalar offsets. B is pre-packed
// (contiguous streams). Schedule identical to round-8 (BK=64, 8 waves, 4 phases/
// K-tile, A 3-deep + B 2-deep = 160 KB, counted VMWAIT(4), setprio around MFMA).
__device__ __forceinline__ void gload_lds16(const void* g, void* l)
{
    __builtin_amdgcn_global_load_lds((const __attribute__((address_space(1))) void*)g,
                                     (__attribute__((address_space(3))) void*)l, 16, 0, 0);
}
#define VMWAIT(n) do { asm volatile("s_waitcnt vmcnt(" #n ")" ::: "memory"); } while (0)
#define PRIO(n)   __builtin_amdgcn_s_setprio(n)
#define SBAR()    __builtin_amdgcn_s_barrier()

#define MFMA_PH(p)                                                                        \
    _Pragma("unroll")                                                                     \
    for (int kk = 0; kk < 2; ++kk)                                                        \
        _Pragma("unroll")                                                                 \
        for (int jj = 0; jj < 2; ++jj)                                                    \
            _Pragma("unroll")                                                             \
            for (int ni = 0; ni < 4; ++ni)                                                \
                acc[2 * (p) + jj][ni] = __builtin_amdgcn_mfma_f32_16x16x32_bf16(          \
                    afv[jj][kk], bfv[ni][kk], acc[2 * (p) + jj][ni], 0, 0, 0);

#define LDA_PH(p)                                                                         \
    _Pragma("unroll")                                                                     \
    for (int jj = 0; jj < 2; ++jj)                                                        \
        _Pragma("unroll")                                                                 \
        for (int kk = 0; kk < 2; ++kk)                                                    \
            afv[jj][kk] = *(const short8*)(Ac + (wm * 8 + 2 * (p) + jj) * 1024 +          \
                                           kk * 512 + lane * 8);

#define KT(ktE, A3, B2, SB, SA, A3n, B2n, VMT) do {                                       \
    const int kt_ = (ktE);                                                                \
    const unsigned short* Ac = lds + (A3) * 16384;                                        \
    const unsigned short* Bc = lds + 49152 + (B2) * 16384;                                \
    short8 bfv[4][2], afv[2][2];                                                          \
    /* ---- phase 0 ---- */                                                               \
    _Pragma("unroll")                                                                     \
    for (int ni = 0; ni < 4; ++ni)                                                        \
        _Pragma("unroll")                                                                 \
        for (int kk = 0; kk < 2; ++kk)                                                    \
            bfv[ni][kk] = *(const short8*)(Bc + (wn * 4 + ni) * 1024 + kk * 512 +         \
                                           lane * 8);                                     \
    LDA_PH(0);                                                                            \
    if (SB) stgB(kt_ + 1, 0, (B2n));                                                      \
    SBAR(); PRIO(1); MFMA_PH(0); PRIO(0); SBAR();                                         \
    /* ---- phase 1 ---- */                                                               \
    LDA_PH(1);                                                                            \
    if (SB) stgB(kt_ + 1, 1, (B2n));                                                      \
    SBAR(); PRIO(1); MFMA_PH(1); PRIO(0); SBAR();                                         \
    /* ---- phase 2 ---- */                                                               \
    LDA_PH(2);                                                                            \
    if (SA) stgA(kt_ + 2, 0, (A3n));                                                      \
    SBAR(); PRIO(1); MFMA_PH(2); PRIO(0); SBAR();                                         \
    /* ---- phase 3 ---- */                                                               \
    LDA_PH(3);                                                                            \
    if (SA) stgA(kt_ + 2, 1, (A3n));                                                      \
    SBAR(); PRIO(1); MFMA_PH(3); PRIO(0);                                                 \
    VMT;                                                                                  \
    SBAR();                                                                               \
} while (0)

__global__ __launch_bounds__(512) void conv_gemm_kernel(const unsigned short* __restrict__ xq,
                                                        const unsigned short* __restrict__ WrP,
                                                        float* __restrict__ out,
                                                        float* __restrict__ sums)
{
    extern __shared__ __align__(16) unsigned short lds[];   // A: 3x16384, B: 2x16384 elems

    const int bid  = blockIdx.x;                    // 0..391
    const int blk  = (bid & 7) * 49 + (bid >> 3);   // bijective XCD swizzle (392 = 8*49)
    const int m0   = blk * 256;
    const int tid  = threadIdx.x;
    const int wv   = tid >> 6;          // 0..7
    const int lane = tid & 63;
    const int ln   = lane & 15;
    const int kg   = lane >> 4;         // 0..3
    const int wm   = wv >> 2;           // 0..1  (M half)
    const int wn   = wv & 3;            // 0..3  (N quarter)

    // per-lane A row bases: row = m0 + (hh*8+wv)*16 + ln -> padded xq elem offset
    // (+ kg*8 k-chunk). Taps/cb add the uniform scalar aoff.
    int abase2[2];
#pragma unroll
    for (int hh = 0; hh < 2; ++hh) {
        int row = m0 + (hh * 8 + wv) * 16 + ln;
        int bb  = row / HW;
        int hw  = row - bb * HW;
        int h   = hw / WW;
        int w   = hw - h * WW;
        abase2[hh] = ((bb * HP + h) * WPAD + w) * CIN + kg * 8;
    }

    auto stgA = [&](int kt2, int h, int a3) {
        const int j  = kt2 >> 2;
        const int kh = j / 3, kw = j - 3 * kh;
        const int aoff = (kh * WPAD + kw) * CIN + (kt2 & 3) * 64;
        unsigned short* dst = lds + a3 * 16384 + (h * 8 + wv) * 1024;
#pragma unroll
        for (int q = 0; q < 2; ++q)
            gload_lds16(xq + abase2[h] + aoff + q * 32, (void*)(dst + q * 512));
    };
    auto stgB = [&](int kt1, int h, int b2) {
        const unsigned short* src = WrP + kt1 * 16384 + (h * 8 + wv) * 1024 + lane * 8;
        unsigned short* dst = lds + 49152 + b2 * 16384 + (h * 8 + wv) * 1024;
#pragma unroll
        for (int q = 0; q < 2; ++q)
            gload_lds16(src + q * 512, (void*)(dst + q * 512));
    };

    f32x4 acc[8][4];
#pragma unroll
    for (int i = 0; i < 8; ++i)
#pragma unroll
        for (int jn = 0; jn < 4; ++jn) acc[i][jn] = (f32x4){0.f, 0.f, 0.f, 0.f};

    // prologue: A(0), A(1), B(0) fully staged (12 loads/thread)
    stgA(0, 0, 0); stgA(0, 1, 0);
    stgA(1, 0, 1); stgA(1, 1, 1);
    stgB(0, 0, 0); stgB(0, 1, 0);
    VMWAIT(0);
    SBAR();

    for (int it = 0; it < 5; ++it) {
        const int k0 = it * 6;
        KT(k0 + 0, 0, 0, 1, 1, 2, 1, VMWAIT(4));
        KT(k0 + 1, 1, 1, 1, 1, 0, 0, VMWAIT(4));
        KT(k0 + 2, 2, 0, 1, 1, 1, 1, VMWAIT(4));
        KT(k0 + 3, 0, 1, 1, 1, 2, 0, VMWAIT(4));
        KT(k0 + 4, 1, 0, 1, 1, 0, 1, VMWAIT(4));
        KT(k0 + 5, 2, 1, 1, 1, 1, 0, VMWAIT(4));
    }
    KT(30, 0, 0, 1, 1, 2, 1, VMWAIT(4));
    KT(31, 1, 1, 1, 1, 0, 0, VMWAIT(4));
    KT(32, 2, 0, 1, 1, 1, 1, VMWAIT(4));
    KT(33, 0, 1, 1, 1, 2, 0, VMWAIT(4));
    KT(34, 1, 0, 1, 0, 0, 1, VMWAIT(0));   // stages B(35) only; drain all
    KT(35, 2, 1, 0, 0, 0, 0, (void)0);     // no staging

    // epilogue: C/D col=lane&15 (n), row=(lane>>4)*4+reg (m). All rows REAL:
    // out index = (row/3136)*802816 + n*3136 + row%3136; quads never straddle
    // rows (56%4==0) or batches (3136%4==0) -> dense f32x4, no masks.
#pragma unroll
    for (int jn = 0; jn < 4; ++jn) {
        const int n = wn * 64 + jn * 16 + ln;
        float s = 0.f, s2 = 0.f;
#pragma unroll
        for (int i = 0; i < 8; ++i) {
            const int row = m0 + wm * 128 + i * 16 + kg * 4;
            const int bb  = row / HW;
            const int hw  = row - bb * HW;
            f32x4 v = acc[i][jn];
            s  += v[0] + v[1] + v[2] + v[3];
            s2 += v[0] * v[0] + v[1] * v[1] + v[2] * v[2] + v[3] * v[3];
            *reinterpret_cast<f32x4*>(&out[(size_t)bb * (COUT * HW) + (size_t)n * HW + hw]) = v;
        }
        s  += __shfl_xor(s, 16);  s  += __shfl_xor(s, 32);
        s2 += __shfl_xor(s2, 16); s2 += __shfl_xor(s2, 32);
        if (kg == 0) {
            atomicAdd(&sums[n], s);
            atomicAdd(&sums[COUT + n], s2);
        }
    }
}

// ---------------- BN normalize + affine + ReLU (in place, f32x4) ----------------
__global__ void bn_apply_kernel(float* __restrict__ y, const float* __restrict__ sums,
                                const float* __restrict__ gamma, const float* __restrict__ beta)
{
    const int o = blockIdx.x, b = blockIdx.y;
    const float N = (float)(BATCH * HH * WW);
    const float mean = sums[o] / N;
    const float var  = sums[COUT + o] / N - mean * mean;
    const float inv  = 1.f / sqrtf(var + 1e-5f);
    const float a  = gamma[o] * inv;
    const float bb = beta[o] - mean * a;
    float* p = y + ((size_t)b * COUT + o) * HW;
    for (int i = threadIdx.x; i < 784; i += 256) {
        f32x4 v = *reinterpret_cast<const f32x4*>(p + i * 4);
#pragma unroll
        for (int r = 0; r < 4; ++r) v[r] = fmaxf(v[r] * a + bb, 0.f);
        *reinterpret_cast<f32x4*>(p + i * 4) = v;
    }
}

extern "C" void kernel_launch(void* const* d_in, const int* in_sizes, int n_in,
                              void* d_out, int out_size, void* d_ws, size_t ws_size,
                              hipStream_t stream)
{
    const float* x     = (const float*)d_in[0];
    const float* Wsrc  = (const float*)d_in[1];
    const float* gamma = (const float*)d_in[2];
    const float* beta  = (const float*)d_in[3];
    float* out = (float*)d_out;

    char* ws = (char*)d_ws;
    const size_t XQ_BYTES = (size_t)BATCH * HP * WPAD * CIN * 2;  // 62,914,560
    const size_t WR_BYTES = (size_t)36 * 16384 * 2;               //  1,179,648
    unsigned short* xq = (unsigned short*)ws;
    unsigned short* wr = (unsigned short*)(ws + XQ_BYTES);
    float* sums = (float*)(ws + XQ_BYTES + WR_BYTES);

    hipMemsetAsync(sums, 0, 2 * COUT * sizeof(float), stream);

    zeropad_kernel<<<dim3(88, BATCH), 256, 0, stream>>>(xq);
    quant_kernel<<<dim3(HH, BATCH), 256, 0, stream>>>(x, xq);
    wrepack_kernel<<<2304, 256, 0, stream>>>(Wsrc, wr);

    hipFuncSetAttribute(reinterpret_cast<const void*>(&conv_gemm_kernel),
                        hipFuncAttributeMaxDynamicSharedMemorySize, 163840);
    conv_gemm_kernel<<<NBLK, 512, 163840, stream>>>(xq, wr, out, sums);

    bn_apply_kernel<<<dim3(COUT, BATCH), 256, 0, stream>>>(out, sums, gamma, beta);
}